// Round 2
// baseline (502.448 us; speedup 1.0000x reference)
//
#include <hip/hip_runtime.h>
#include <stdint.h>
#include <stddef.h>

#define IN_F 4096
#define OUT_F 4096
#define M_TOT 8192

// fused-fallback tile
#define BM 128
#define BN 128
#define BK 64

// main GEMM tile
#define BM2 256
#define BN2 256
#define BK2 64
#define NT2 (IN_F / BK2)   // 64 K-tiles

typedef __attribute__((ext_vector_type(8))) short short8;     // 8 x bf16 (4 VGPRs) MFMA A/B frag
typedef __attribute__((ext_vector_type(4))) float f32x4;      // MFMA C/D frag
typedef __attribute__((ext_vector_type(4))) float float4v;
typedef __attribute__((ext_vector_type(4))) unsigned short u16x4;
typedef __attribute__((ext_vector_type(8))) unsigned short u16x8;
typedef unsigned short u16;

// FP4 codebook (matches reference FP4_CODEBOOK exactly)
__constant__ float c_lut[16] = {
  0.0f, 0.0052f, 0.6667f, 1.0f, 0.3333f, 0.5f, 0.1667f, 0.25f,
  0.0f, -0.0052f, -0.6667f, -1.0f, -0.3333f, -0.5f, -0.1667f, -0.25f
};

// fp32 -> bf16 round-to-nearest-even
__device__ __forceinline__ u16 f2bf(float f) {
  unsigned int x = __float_as_uint(f);
  x += 0x7fffu + ((x >> 16) & 1u);
  return (u16)(x >> 16);
}

// async global->LDS, 16B per lane. LDS dest is wave-uniform base + lane*16.
__device__ __forceinline__ void gload_lds16(const u16* g, u16* lds) {
  __builtin_amdgcn_global_load_lds(
      (const __attribute__((address_space(1))) unsigned int*)g,
      (__attribute__((address_space(3))) unsigned int*)lds, 16, 0, 0);
}

#define BARRIER() do { asm volatile("" ::: "memory"); \
                       __builtin_amdgcn_s_barrier();  \
                       asm volatile("" ::: "memory"); } while (0)
#define LGKM0() asm volatile("s_waitcnt lgkmcnt(0)" ::: "memory")

// ---------------- merged prep: W dequant (blocks 0..511) + x convert ----------------
__global__ __launch_bounds__(256) void k_prep(const float* __restrict__ x,
                                              u16* __restrict__ a,
                                              const int* __restrict__ wp,
                                              const float* __restrict__ scale,
                                              u16* __restrict__ b) {
  if (blockIdx.x < 512) {
    // ---- W: packed fp4 -> bf16 (N x K, k-major) ----
    __shared__ float lut[16];
    if (threadIdx.x < 16) lut[threadIdx.x] = c_lut[threadIdx.x];
    __syncthreads();
    const int ng = (OUT_F * IN_F / 2) / 4;  // int4 groups
    const int stride = 512 * 256;
    for (int t = blockIdx.x * 256 + threadIdx.x; t < ng; t += stride) {
      int4 p = ((const int4*)wp)[t];
      float s = scale[t >> 3];
      int by[4] = {p.x, p.y, p.z, p.w};
      u16x8 o;
#pragma unroll
      for (int q = 0; q < 4; ++q) {
        o[2 * q]     = f2bf(lut[(by[q] >> 4) & 15] * s);
        o[2 * q + 1] = f2bf(lut[by[q] & 15] * s);
      }
      ((u16x8*)b)[t] = o;
    }
  } else {
    // ---- x: fp32 -> bf16 (M x K, k-major) ----
    const int n8 = (M_TOT * IN_F) / 8;
    const int stride = 4096 * 256;
    for (int t = (blockIdx.x - 512) * 256 + threadIdx.x; t < n8; t += stride) {
      float4v f0 = ((const float4v*)x)[2 * t];
      float4v f1 = ((const float4v*)x)[2 * t + 1];
      u16x8 o;
      o[0] = f2bf(f0.x); o[1] = f2bf(f0.y); o[2] = f2bf(f0.z); o[3] = f2bf(f0.w);
      o[4] = f2bf(f1.x); o[5] = f2bf(f1.y); o[6] = f2bf(f1.z); o[7] = f2bf(f1.w);
      ((u16x8*)a)[t] = o;
    }
  }
}

// ===================== 256x256 pipelined GEMM, B-resident / A-streamed =====================
// C = A(bf16, MxK) * B(bf16, NxK)^T + bias
// 512 thr / 8 waves (2M x 4N), per-wave output 128x64 = acc[8][4] 16x16 frags.
// Per K-tile: B held in regs b[4][2] (read once, P1-boundary), A streamed a[2][2].
// 4 phases x 16 MFMA; phase p's ds_reads are issued AFTER phase p-1's MFMA so they
// complete under the MFMA tail + barrier; lgkmcnt(0) at phase top finds them done.
// ONE barrier per phase: a freed region's reads complete at that phase's lgkm(0)
// (before its closing barrier), so next phase's global_load_lds can't race them.
// Staging rounds (8 KB each, 1 gload/wave): tile t stages
//   P1: A3(t+1)->other buf   (a67(t-1) rows, freed at P4(t-1))
//   P2: B01+A0(t+2)->cur buf (B+a01 freed at P1)
//   P3: B23+A1(t+2)->cur buf (a23 freed at P2)
//   P4: A2(t+2)->cur buf     (a45 freed at P3)
// vmcnt(7) at P4 = exactly drains A2(t+1),A3(t+1) (7 younger rounds stay in flight);
// then the 12 tile-boundary reads (b+a01 of t+1) issue from the other buffer.
// LDS chunk-XOR swizzle unchanged: LDS 16B-chunk p of row r holds GLOBAL chunk p^(r&7).

__device__ __forceinline__ void stage_b_round(const u16* __restrict__ B, u16* dst,
                                              int nBase, int kt, int r,
                                              int wave, int srow, int scol) {
  const int r0 = r * 64 + wave * 8;               // wave-uniform, multiple of 8
  gload_lds16(B + (size_t)(nBase + r0 + srow) * IN_F + kt + scol, dst + r0 * BK2);
}

__device__ __forceinline__ void stage_a_round(const u16* __restrict__ A, u16* dst,
                                              int mBase, int kt, int r,
                                              int wave, int srow, int scol) {
  const int r0 = (wave & 3) * 8 + (wave >> 2) * 128 + r * 32;
  gload_lds16(A + (size_t)(mBase + r0 + srow) * IN_F + kt + scol, dst + r0 * BK2);
}

__device__ __forceinline__ void read_b_all(const u16* Bs_c, int bBase, int co0, int co1,
                                           short8 b[4][2]) {
#pragma unroll
  for (int jj = 0; jj < 4; ++jj) {
    const int ro = bBase + jj * (16 * BK2);
    b[jj][0] = *(const short8*)&Bs_c[ro + co0];
    b[jj][1] = *(const short8*)&Bs_c[ro + co1];
  }
}

__device__ __forceinline__ void read_a_pair(const u16* As_c, int aBase, int co0, int co1,
                                            short8 a[2][2], int p) {
#pragma unroll
  for (int ii = 0; ii < 2; ++ii) {
    const int ro = aBase + (p * 2 + ii) * (16 * BK2);
    a[ii][0] = *(const short8*)&As_c[ro + co0];
    a[ii][1] = *(const short8*)&As_c[ro + co1];
  }
}

__device__ __forceinline__ void mma_pair(f32x4 acc[8][4], const short8 a[2][2],
                                         const short8 b[4][2], int p) {
#pragma unroll
  for (int k2 = 0; k2 < 2; ++k2)
#pragma unroll
    for (int ii = 0; ii < 2; ++ii)
#pragma unroll
      for (int jj = 0; jj < 4; ++jj)
        acc[p * 2 + ii][jj] = __builtin_amdgcn_mfma_f32_16x16x32_bf16(
            a[ii][k2], b[jj][k2], acc[p * 2 + ii][jj], 0, 0, 0);
}

__global__ __launch_bounds__(512, 2) void k_gemm256(const u16* __restrict__ A,
                                                    const u16* __restrict__ B,
                                                    const float* __restrict__ bias,
                                                    float* __restrict__ C) {
  __shared__ u16 As[2][BM2 * BK2];   // 2 x 32 KiB
  __shared__ u16 Bs[2][BN2 * BK2];   // 2 x 32 KiB

  const int tid  = threadIdx.x;
  const int lane = tid & 63;
  const int wave = tid >> 6;

  // XCD-aware tile swizzle: 8x8 tile square per XCD (grid 32x16 = 512, %8==0)
  const int bid   = blockIdx.x;
  const int xcd   = bid & 7;
  const int k     = bid >> 3;
  const int tileM = (xcd >> 1) * 8 + (k >> 3);
  const int tileN = (xcd & 1) * 8 + (k & 7);
  const int mBase = tileM * BM2;
  const int nBase = tileN * BN2;

  const int wm = (wave >> 2) * 128;
  const int wn = (wave & 3) * 64;

  // staging lane decomposition (8 rows x 64 cols per gload, XOR-swizzled source)
  const int srow = lane >> 3;
  const int scol = ((lane & 7) ^ srow) * 8;

  // MFMA operand addressing
  const int frow = lane & 15;
  const int fx   = frow & 7;
  const int cq   = lane >> 4;
  const int co0  = ((cq ^ fx) << 3);
  const int co1  = (((4 + cq) ^ fx) << 3);
  const int aBase = (wm + frow) * BK2;
  const int bBase = (wn + frow) * BK2;

  f32x4 acc[8][4] = {};
  short8 a[2][2], b[4][2];

#define SB(dst, t, r) stage_b_round(B, dst, nBase, (t) * BK2, r, wave, srow, scol)
#define SA(dst, t, r) stage_a_round(A, dst, mBase, (t) * BK2, r, wave, srow, scol)

  // ---- prologue: tile0 (8 rounds) + tile1 {B01,A0,B23,A1,A2} (7 rounds) ----
  SB(Bs[0], 0, 0); SB(Bs[0], 0, 1); SB(Bs[0], 0, 2); SB(Bs[0], 0, 3);
  SA(As[0], 0, 0); SA(As[0], 0, 1); SA(As[0], 0, 2); SA(As[0], 0, 3);
  SB(Bs[1], 1, 0); SB(Bs[1], 1, 1); SA(As[1], 1, 0);
  SB(Bs[1], 1, 2); SB(Bs[1], 1, 3); SA(As[1], 1, 1);
  SA(As[1], 1, 2);
  asm volatile("s_waitcnt vmcnt(7)" ::: "memory");   // tile0's 8 rounds landed
  BARRIER();
  read_b_all(Bs[0], bBase, co0, co1, b);
  read_a_pair(As[0], aBase, co0, co1, a, 0);

  for (int t = 0; t < NT2; ++t) {
    const int c = t & 1;
    u16* AsC = As[c];
    u16* BsC = Bs[c];
    u16* AsO = As[c ^ 1];
    u16* BsO = Bs[c ^ 1];

    // ---- P1: mma(a01 x B); stage A3(t+1)->other; then read a23 ----
    if (t + 1 < NT2) SA(AsO, t + 1, 3);
    LGKM0();                                   // b + a01 ready (issued last phase)
    __builtin_amdgcn_s_setprio(1);
    mma_pair(acc, a, b, 0);
    __builtin_amdgcn_s_setprio(0);
    read_a_pair(AsC, aBase, co0, co1, a, 1);   // serviced under barrier + P2 head
    BARRIER();

    // ---- P2: mma(a23 x B); stage B01+A0(t+2)->cur; then read a45 ----
    if (t + 2 < NT2) { SB(BsC, t + 2, 0); SB(BsC, t + 2, 1); SA(AsC, t + 2, 0); }
    LGKM0();
    __builtin_amdgcn_s_setprio(1);
    mma_pair(acc, a, b, 1);
    __builtin_amdgcn_s_setprio(0);
    read_a_pair(AsC, aBase, co0, co1, a, 2);
    BARRIER();

    // ---- P3: mma(a45 x B); stage B23+A1(t+2)->cur; then read a67 ----
    if (t + 2 < NT2) { SB(BsC, t + 2, 2); SB(BsC, t + 2, 3); SA(AsC, t + 2, 1); }
    LGKM0();
    __builtin_amdgcn_s_setprio(1);
    mma_pair(acc, a, b, 2);
    __builtin_amdgcn_s_setprio(0);
    read_a_pair(AsC, aBase, co0, co1, a, 3);
    BARRIER();

    // ---- P4: mma(a67 x B); stage A2(t+2)->cur; vmcnt(7); read b+a01 of t+1 ----
    if (t + 2 < NT2) SA(AsC, t + 2, 2);
    LGKM0();
    __builtin_amdgcn_s_setprio(1);
    mma_pair(acc, a, b, 3);
    __builtin_amdgcn_s_setprio(0);
    if (t + 1 < NT2) {
      if (t < NT2 - 2) asm volatile("s_waitcnt vmcnt(7)" ::: "memory");
      else             asm volatile("s_waitcnt vmcnt(0)" ::: "memory");
      read_b_all(BsO, bBase, co0, co1, b);
      read_a_pair(AsO, aBase, co0, co1, a, 0);
    }
    BARRIER();
  }

#undef SB
#undef SA

  // epilogue: C/D layout col = lane&15, row = (lane>>4)*4 + reg   [m89-verified]
  const int ccol = lane & 15;
  const int crow = (lane >> 4) * 4;
#pragma unroll
  for (int j = 0; j < 4; ++j) {
    const int col = nBase + wn + j * 16 + ccol;
    const float bv = bias[col];
#pragma unroll
    for (int i = 0; i < 8; ++i) {
      const size_t rb = (size_t)(mBase + wm + i * 16 + crow) * OUT_F + col;
#pragma unroll
      for (int tt = 0; tt < 4; ++tt)
        C[rb + (size_t)tt * OUT_F] = acc[i][j][tt] + bv;
    }
  }
}

// -------- fallback: fully fused (no workspace), register-staged conversion --------
__global__ __launch_bounds__(256) void k_gemm_fused(const float* __restrict__ X,
                                                    const int* __restrict__ WP,
                                                    const float* __restrict__ scale,
                                                    const float* __restrict__ bias,
                                                    float* __restrict__ C) {
  __shared__ u16 As[BM * BK];
  __shared__ u16 Bs[BN * BK];
  __shared__ float lut[16];
  const int tid = threadIdx.x;
  if (tid < 16) lut[tid] = c_lut[tid];
  const int lane = tid & 63;
  const int wave = tid >> 6;
  const int mBase = blockIdx.y * BM;
  const int nBase = blockIdx.x * BN;
  const int wm = (wave >> 1) * 64;
  const int wn = (wave & 1) * 64;
  const int frow = lane & 15;
  const int fx   = lane & 7;
  const int cq   = lane >> 4;
  f32x4 acc[4][4] = {};
  __syncthreads();  // lut ready

  for (int kt = 0; kt < IN_F; kt += BK) {
#pragma unroll
    for (int i = 0; i < 8; ++i) {
      const int g = tid + i * 256;
      const int r = g >> 4, c = (g & 15) * 4;
      float4v f = *(const float4v*)&X[(size_t)(mBase + r) * IN_F + kt + c];
      u16x4 o;
      o.x = f2bf(f.x); o.y = f2bf(f.y); o.z = f2bf(f.z); o.w = f2bf(f.w);
      *(u16x4*)&As[r * BK + ((((c >> 3) ^ (r & 7)) << 3) | (c & 7))] = o;
    }
#pragma unroll
    for (int i = 0; i < 4; ++i) {
      const int g = tid + i * 256;
      const int r = g >> 3, c4 = (g & 7) * 4;
      int4 p = *(const int4*)&WP[(size_t)(nBase + r) * (IN_F / 2) + (kt >> 1) + c4];
      const float s = scale[(nBase + r) * 64 + (kt >> 6)];
      int by[4] = {p.x, p.y, p.z, p.w};
      u16x8 o;
#pragma unroll
      for (int q = 0; q < 4; ++q) {
        o[2 * q]     = f2bf(lut[(by[q] >> 4) & 15] * s);
        o[2 * q + 1] = f2bf(lut[by[q] & 15] * s);
      }
      *(u16x8*)&Bs[r * BK + (((g & 7) ^ (r & 7)) << 3)] = o;
    }
    __syncthreads();
#pragma unroll
    for (int ks = 0; ks < BK; ks += 32) {
      const int co = (((ks >> 3) + cq) ^ fx) << 3;
      short8 a[4], b[4];
#pragma unroll
      for (int i = 0; i < 4; ++i)
        a[i] = *(const short8*)&As[(wm + i * 16 + frow) * BK + co];
#pragma unroll
      for (int j = 0; j < 4; ++j)
        b[j] = *(const short8*)&Bs[(wn + j * 16 + frow) * BK + co];
#pragma unroll
      for (int i = 0; i < 4; ++i)
#pragma unroll
        for (int j = 0; j < 4; ++j)
          acc[i][j] = __builtin_amdgcn_mfma_f32_16x16x32_bf16(a[i], b[j], acc[i][j], 0, 0, 0);
    }
    __syncthreads();
  }

  const int ccol = lane & 15;
  const int crow = (lane >> 4) * 4;
#pragma unroll
  for (int j = 0; j < 4; ++j) {
    const int col = nBase + wn + j * 16 + ccol;
    const float bv = bias[col];
#pragma unroll
    for (int i = 0; i < 4; ++i) {
      const size_t rb = (size_t)(mBase + wm + i * 16 + crow) * OUT_F + col;
#pragma unroll
      for (int t = 0; t < 4; ++t)
        C[rb + (size_t)t * OUT_F] = acc[i][j][t] + bv;
    }
  }
}

extern "C" void kernel_launch(void* const* d_in, const int* in_sizes, int n_in,
                              void* d_out, int out_size, void* d_ws, size_t ws_size,
                              hipStream_t stream) {
  const float* x  = (const float*)d_in[0];
  const int*   wp = (const int*)d_in[1];
  const float* sc = (const float*)d_in[2];
  const float* bi = (const float*)d_in[3];
  float* out = (float*)d_out;

  const size_t bBytes = (size_t)OUT_F * IN_F * 2;   // 33.5 MB bf16 W
  const size_t aBytes = (size_t)M_TOT * IN_F * 2;   // 67 MB bf16 x

  if (ws_size >= aBytes + bBytes) {
    u16* B = (u16*)d_ws;
    u16* A = (u16*)((char*)d_ws + bBytes);
    k_prep<<<4608, 256, 0, stream>>>(x, A, wp, sc, B);
    k_gemm256<<<(M_TOT / BM2) * (OUT_F / BN2), 512, 0, stream>>>(A, B, bi, out);
  } else {
    dim3 grid(OUT_F / BN, M_TOT / BM);
    k_gemm_fused<<<grid, 256, 0, stream>>>(x, wp, sc, bi, out);
  }
}

// Round 3
// 483.730 us; speedup vs baseline: 1.0387x; 1.0387x over previous
//
#include <hip/hip_runtime.h>
#include <stdint.h>
#include <stddef.h>

#define IN_F 4096
#define OUT_F 4096
#define M_TOT 8192

// fused-fallback tile
#define BM 128
#define BN 128
#define BK 64

// main GEMM tile
#define BM2 256
#define BN2 256
#define BK2 64
#define NT2 (IN_F / BK2)   // 64 K-tiles

typedef __attribute__((ext_vector_type(8))) short short8;     // 8 x bf16 (4 VGPRs) MFMA A/B frag
typedef __attribute__((ext_vector_type(4))) float f32x4;      // MFMA C/D frag
typedef __attribute__((ext_vector_type(4))) float float4v;
typedef __attribute__((ext_vector_type(4))) unsigned short u16x4;
typedef __attribute__((ext_vector_type(8))) unsigned short u16x8;
typedef unsigned short u16;

// FP4 codebook (matches reference FP4_CODEBOOK exactly)
__constant__ float c_lut[16] = {
  0.0f, 0.0052f, 0.6667f, 1.0f, 0.3333f, 0.5f, 0.1667f, 0.25f,
  0.0f, -0.0052f, -0.6667f, -1.0f, -0.3333f, -0.5f, -0.1667f, -0.25f
};

// fp32 -> bf16 round-to-nearest-even
__device__ __forceinline__ u16 f2bf(float f) {
  unsigned int x = __float_as_uint(f);
  x += 0x7fffu + ((x >> 16) & 1u);
  return (u16)(x >> 16);
}

// async global->LDS, 16B per lane. LDS dest is wave-uniform base + lane*16.
__device__ __forceinline__ void gload_lds16(const u16* g, u16* lds) {
  __builtin_amdgcn_global_load_lds(
      (const __attribute__((address_space(1))) unsigned int*)g,
      (__attribute__((address_space(3))) unsigned int*)lds, 16, 0, 0);
}

// raw barrier; counted waits handle data deps (no full vmcnt/lgkm drain).
#define BARRIER() do { asm volatile("" ::: "memory"); \
                       __builtin_amdgcn_s_barrier();  \
                       asm volatile("" ::: "memory"); } while (0)
// counted lgkm wait + scheduler pin (rule #18: stops MFMA hoisting past the wait)
#define LGW(n) do { asm volatile("s_waitcnt lgkmcnt(" #n ")" ::: "memory"); \
                    __builtin_amdgcn_sched_barrier(0); } while (0)
#define VMW(n) asm volatile("s_waitcnt vmcnt(" #n ")" ::: "memory")

// ---------------- merged prep: W dequant (blocks 0..511) + x convert ----------------
__global__ __launch_bounds__(256) void k_prep(const float* __restrict__ x,
                                              u16* __restrict__ a,
                                              const int* __restrict__ wp,
                                              const float* __restrict__ scale,
                                              u16* __restrict__ b) {
  if (blockIdx.x < 512) {
    __shared__ float lut[16];
    if (threadIdx.x < 16) lut[threadIdx.x] = c_lut[threadIdx.x];
    __syncthreads();
    const int ng = (OUT_F * IN_F / 2) / 4;  // int4 groups
    const int stride = 512 * 256;
    for (int t = blockIdx.x * 256 + threadIdx.x; t < ng; t += stride) {
      int4 p = ((const int4*)wp)[t];
      float s = scale[t >> 3];
      int by[4] = {p.x, p.y, p.z, p.w};
      u16x8 o;
#pragma unroll
      for (int q = 0; q < 4; ++q) {
        o[2 * q]     = f2bf(lut[(by[q] >> 4) & 15] * s);
        o[2 * q + 1] = f2bf(lut[by[q] & 15] * s);
      }
      ((u16x8*)b)[t] = o;
    }
  } else {
    const int n8 = (M_TOT * IN_F) / 8;
    const int stride = 4096 * 256;
    for (int t = (blockIdx.x - 512) * 256 + threadIdx.x; t < n8; t += stride) {
      float4v f0 = ((const float4v*)x)[2 * t];
      float4v f1 = ((const float4v*)x)[2 * t + 1];
      u16x8 o;
      o[0] = f2bf(f0.x); o[1] = f2bf(f0.y); o[2] = f2bf(f0.z); o[3] = f2bf(f0.w);
      o[4] = f2bf(f1.x); o[5] = f2bf(f1.y); o[6] = f2bf(f1.z); o[7] = f2bf(f1.w);
      ((u16x8*)a)[t] = o;
    }
  }
}

// ===================== 256x256 read-ahead pipelined GEMM =====================
// C = A(bf16, MxK) * B(bf16, NxK)^T + bias. 512 thr / 8 waves (2M x 4N),
// per-wave output 128x64 = acc[8][4] 16x16x32 frags. 4 phases/K-tile, 1 barrier
// each, 16 MFMA each: P1 aC*b0, P2 aC*b1, P3 aN*b1, P4 aN*b0.
//
// KEY MECHANISM (counted lgkm read-ahead): each phase-top issues ds_reads whose
// results are needed LATER; counted s_waitcnt lgkmcnt(N) (DS completes in-order)
// drains only what the MFMA cluster needs, leaving younger reads in flight
// THROUGH the MFMA — LDS service overlaps the matrix pipe.
//   P1-top: rd B0_t(4) then B1_t(4)   -> LGW(4): B1 stays in flight during MFMA
//   P2-top: rd A1_t(8)                -> LGW(8): A1 in flight during MFMA P2
//   P3-top: none                      -> LGW(0) drains A1
//   P4-top: rd A0_{t+1}(8)            -> no wait: in flight during MFMA P4
//
// Staging (8 gload rounds/tile, region = last-read + 2 phases before overwrite):
//   P1/P2(t): A1_{t+1} k0/k1 -> other buf   (A1 free from P1(t+1)- shifted)
//   P3(t):    B0,B0,A0k0 of t+2 -> cur      (B0/A0 regions free from P3(t))
//   P4(t):    A0k1,B1,B1 of t+2 -> cur      (B1 free from P4(t))
// vmcnt: VMW(6)@P1-top (drains A1_t rounds, 3-4 phases old, pre-barrier(P1) ->
// safe for P2-top reads); VMW(2)@P3-top (drains t+1's B/A0 rounds, 3-4 phases
// old, pre-barrier(P3) -> safe for P4-top and next P1-top reads). Never vmcnt(0)
// in steady state; all cross-buffer ds_reads are covered by a pre-barrier vmcnt
// (publish-safety across waves).
// LDS chunk-XOR swizzle: LDS 16B-chunk p of row r holds GLOBAL chunk p^(r&7).

__device__ __forceinline__ void st_b(const u16* __restrict__ B, u16* dst,
                                     int nBase, int kt, int h, int k,
                                     int wave, int srow, int scol) {
  const int r0 = 64 * (wave >> 1) + 32 * h + 16 * k + 8 * (wave & 1);
  gload_lds16(B + (size_t)(nBase + r0 + srow) * IN_F + kt + scol, dst + r0 * BK2);
}
__device__ __forceinline__ void st_a(const u16* __restrict__ A, u16* dst,
                                     int mBase, int kt, int h, int k,
                                     int wave, int srow, int scol) {
  const int r0 = 128 * (wave >> 2) + 64 * h + 32 * k + 8 * (wave & 3);
  gload_lds16(A + (size_t)(mBase + r0 + srow) * IN_F + kt + scol, dst + r0 * BK2);
}

__device__ __forceinline__ void rd_b(short8 d[2][2], const u16* Bs_c, int bBase,
                                     int co0, int co1, int h) {
#pragma unroll
  for (int jj = 0; jj < 2; ++jj) {
    const int ro = bBase + (h * 2 + jj) * (16 * BK2);
    d[jj][0] = *(const short8*)&Bs_c[ro + co0];
    d[jj][1] = *(const short8*)&Bs_c[ro + co1];
  }
}
__device__ __forceinline__ void rd_a(short8 d[4][2], const u16* As_c, int aBase,
                                     int co0, int co1, int h) {
#pragma unroll
  for (int ii = 0; ii < 4; ++ii) {
    const int ro = aBase + (h * 4 + ii) * (16 * BK2);
    d[ii][0] = *(const short8*)&As_c[ro + co0];
    d[ii][1] = *(const short8*)&As_c[ro + co1];
  }
}
__device__ __forceinline__ void mma8(f32x4 acc[8][4], const short8 a[4][2],
                                     const short8 b[2][2], int i0, int j0) {
#pragma unroll
  for (int k2 = 0; k2 < 2; ++k2)
#pragma unroll
    for (int ii = 0; ii < 4; ++ii)
#pragma unroll
      for (int jj = 0; jj < 2; ++jj)
        acc[i0 + ii][j0 + jj] = __builtin_amdgcn_mfma_f32_16x16x32_bf16(
            a[ii][k2], b[jj][k2], acc[i0 + ii][j0 + jj], 0, 0, 0);
}

__global__ __launch_bounds__(512, 2) void k_gemm256(const u16* __restrict__ A,
                                                    const u16* __restrict__ B,
                                                    const float* __restrict__ bias,
                                                    float* __restrict__ C) {
  __shared__ u16 As[2][BM2 * BK2];   // 2 x 32 KiB
  __shared__ u16 Bs[2][BN2 * BK2];   // 2 x 32 KiB

  const int tid  = threadIdx.x;
  const int lane = tid & 63;
  const int wave = tid >> 6;

  // XCD-aware tile swizzle: 8x8 tile square per XCD (grid 32x16 = 512, %8==0)
  const int bid   = blockIdx.x;
  const int xcd   = bid & 7;
  const int kk    = bid >> 3;
  const int tileM = (xcd >> 1) * 8 + (kk >> 3);
  const int tileN = (xcd & 1) * 8 + (kk & 7);
  const int mBase = tileM * BM2;
  const int nBase = tileN * BN2;

  const int wm = (wave >> 2) * 128;
  const int wn = (wave & 3) * 64;

  // staging lane decomposition (8 rows x 64 cols per gload, XOR-swizzled source)
  const int srow = lane >> 3;
  const int scol = ((lane & 7) ^ srow) * 8;

  // MFMA operand addressing
  const int frow = lane & 15;
  const int fx   = frow & 7;
  const int cq   = lane >> 4;
  const int co0  = ((cq ^ fx) << 3);
  const int co1  = (((4 + cq) ^ fx) << 3);
  const int aBase = (wm + frow) * BK2;
  const int bBase = (wn + frow) * BK2;

  f32x4 acc[8][4] = {};
  short8 aC[4][2], aN[4][2], b0[2][2], b1[2][2];

  // ---- prologue: tile0 full (8 rounds) + tile1 {B0,B0,A0,A0,B1,B1} (6) ----
  st_b(B, Bs[0], nBase, 0, 0, 0, wave, srow, scol);
  st_b(B, Bs[0], nBase, 0, 0, 1, wave, srow, scol);
  st_b(B, Bs[0], nBase, 0, 1, 0, wave, srow, scol);
  st_b(B, Bs[0], nBase, 0, 1, 1, wave, srow, scol);
  st_a(A, As[0], mBase, 0, 0, 0, wave, srow, scol);
  st_a(A, As[0], mBase, 0, 0, 1, wave, srow, scol);
  st_a(A, As[0], mBase, 0, 1, 0, wave, srow, scol);
  st_a(A, As[0], mBase, 0, 1, 1, wave, srow, scol);
  st_b(B, Bs[1], nBase, BK2, 0, 0, wave, srow, scol);
  st_b(B, Bs[1], nBase, BK2, 0, 1, wave, srow, scol);
  st_a(A, As[1], mBase, BK2, 0, 0, wave, srow, scol);
  st_a(A, As[1], mBase, BK2, 0, 1, wave, srow, scol);
  st_b(B, Bs[1], nBase, BK2, 1, 0, wave, srow, scol);
  st_b(B, Bs[1], nBase, BK2, 1, 1, wave, srow, scol);
  VMW(6);            // tile0's 8 rounds landed; tile1's 6 stay in flight
  BARRIER();
  rd_a(aC, As[0], aBase, co0, co1, 0);   // A0_0 (8 reads, in flight into P1)

  for (int t = 0; t < NT2; ++t) {
    const int c = t & 1;
    u16* AsC = As[c];
    u16* BsC = Bs[c];
    u16* AsO = As[c ^ 1];

    // ---------- P1: MFMA aC x b0 ----------
    if (t < NT2 - 1) { VMW(6); } else { VMW(0); }   // drain A1_t stage rounds
    rd_b(b0, BsC, bBase, co0, co1, 0);              // B0_t (drained at LGW(4))
    __builtin_amdgcn_sched_barrier(0);              // pin group order: b0 older
    rd_b(b1, BsC, bBase, co0, co1, 1);              // B1_t (kept in flight)
    if (t + 1 < NT2) st_a(A, AsO, mBase, (t + 1) * BK2, 1, 0, wave, srow, scol);
    BARRIER();
    LGW(4);                                         // A0_t + B0_t done; B1 flying
    __builtin_amdgcn_s_setprio(1);
    mma8(acc, aC, b0, 0, 0);
    __builtin_amdgcn_s_setprio(0);

    // ---------- P2: MFMA aC x b1 ----------
    rd_a(aN, AsC, aBase, co0, co1, 1);              // A1_t (kept in flight)
    if (t + 1 < NT2) st_a(A, AsO, mBase, (t + 1) * BK2, 1, 1, wave, srow, scol);
    BARRIER();
    LGW(8);                                         // B1 done; A1 flying
    __builtin_amdgcn_s_setprio(1);
    mma8(acc, aC, b1, 0, 2);
    __builtin_amdgcn_s_setprio(0);

    // ---------- P3: MFMA aN x b1 ----------
    VMW(2);                                         // drain t+1's B/A0 rounds
    if (t + 2 < NT2) {
      st_b(B, BsC, nBase, (t + 2) * BK2, 0, 0, wave, srow, scol);
      st_b(B, BsC, nBase, (t + 2) * BK2, 0, 1, wave, srow, scol);
      st_a(A, AsC, mBase, (t + 2) * BK2, 0, 0, wave, srow, scol);
    }
    BARRIER();
    LGW(0);                                         // A1 done
    __builtin_amdgcn_s_setprio(1);
    mma8(acc, aN, b1, 4, 2);
    __builtin_amdgcn_s_setprio(0);

    // ---------- P4: MFMA aN x b0 ----------
    if (t + 1 < NT2) rd_a(aC, AsO, aBase, co0, co1, 0);  // A0_{t+1} (flying)
    if (t + 2 < NT2) {
      st_a(A, AsC, mBase, (t + 2) * BK2, 0, 1, wave, srow, scol);
      st_b(B, BsC, nBase, (t + 2) * BK2, 1, 0, wave, srow, scol);
      st_b(B, BsC, nBase, (t + 2) * BK2, 1, 1, wave, srow, scol);
    }
    BARRIER();
    __builtin_amdgcn_s_setprio(1);                  // deps drained at P3's LGW(0)
    mma8(acc, aN, b0, 4, 0);
    __builtin_amdgcn_s_setprio(0);
  }

  // epilogue: C/D layout col = lane&15, row = (lane>>4)*4 + reg   [m89-verified]
  const int ccol = lane & 15;
  const int crow = (lane >> 4) * 4;
#pragma unroll
  for (int j = 0; j < 4; ++j) {
    const int col = nBase + wn + j * 16 + ccol;
    const float bv = bias[col];
#pragma unroll
    for (int i = 0; i < 8; ++i) {
      const size_t rb = (size_t)(mBase + wm + i * 16 + crow) * OUT_F + col;
#pragma unroll
      for (int tt = 0; tt < 4; ++tt)
        C[rb + (size_t)tt * OUT_F] = acc[i][j][tt] + bv;
    }
  }
}

// -------- fallback: fully fused (no workspace), register-staged conversion --------
__global__ __launch_bounds__(256) void k_gemm_fused(const float* __restrict__ X,
                                                    const int* __restrict__ WP,
                                                    const float* __restrict__ scale,
                                                    const float* __restrict__ bias,
                                                    float* __restrict__ C) {
  __shared__ u16 As[BM * BK];
  __shared__ u16 Bs[BN * BK];
  __shared__ float lut[16];
  const int tid = threadIdx.x;
  if (tid < 16) lut[tid] = c_lut[tid];
  const int lane = tid & 63;
  const int wave = tid >> 6;
  const int mBase = blockIdx.y * BM;
  const int nBase = blockIdx.x * BN;
  const int wm = (wave >> 1) * 64;
  const int wn = (wave & 1) * 64;
  const int frow = lane & 15;
  const int fx   = lane & 7;
  const int cq   = lane >> 4;
  f32x4 acc[4][4] = {};
  __syncthreads();  // lut ready

  for (int kt = 0; kt < IN_F; kt += BK) {
#pragma unroll
    for (int i = 0; i < 8; ++i) {
      const int g = tid + i * 256;
      const int r = g >> 4, c = (g & 15) * 4;
      float4v f = *(const float4v*)&X[(size_t)(mBase + r) * IN_F + kt + c];
      u16x4 o;
      o.x = f2bf(f.x); o.y = f2bf(f.y); o.z = f2bf(f.z); o.w = f2bf(f.w);
      *(u16x4*)&As[r * BK + ((((c >> 3) ^ (r & 7)) << 3) | (c & 7))] = o;
    }
#pragma unroll
    for (int i = 0; i < 4; ++i) {
      const int g = tid + i * 256;
      const int r = g >> 3, c4 = (g & 7) * 4;
      int4 p = *(const int4*)&WP[(size_t)(nBase + r) * (IN_F / 2) + (kt >> 1) + c4];
      const float s = scale[(nBase + r) * 64 + (kt >> 6)];
      int by[4] = {p.x, p.y, p.z, p.w};
      u16x8 o;
#pragma unroll
      for (int q = 0; q < 4; ++q) {
        o[2 * q]     = f2bf(lut[(by[q] >> 4) & 15] * s);
        o[2 * q + 1] = f2bf(lut[by[q] & 15] * s);
      }
      *(u16x8*)&Bs[r * BK + (((g & 7) ^ (r & 7)) << 3)] = o;
    }
    __syncthreads();
#pragma unroll
    for (int ks = 0; ks < BK; ks += 32) {
      const int co = (((ks >> 3) + cq) ^ fx) << 3;
      short8 a[4], b[4];
#pragma unroll
      for (int i = 0; i < 4; ++i)
        a[i] = *(const short8*)&As[(wm + i * 16 + frow) * BK + co];
#pragma unroll
      for (int j = 0; j < 4; ++j)
        b[j] = *(const short8*)&Bs[(wn + j * 16 + frow) * BK + co];
#pragma unroll
      for (int i = 0; i < 4; ++i)
#pragma unroll
        for (int j = 0; j < 4; ++j)
          acc[i][j] = __builtin_amdgcn_mfma_f32_16x16x32_bf16(a[i], b[j], acc[i][j], 0, 0, 0);
    }
    __syncthreads();
  }

  const int ccol = lane & 15;
  const int crow = (lane >> 4) * 4;
#pragma unroll
  for (int j = 0; j < 4; ++j) {
    const int col = nBase + wn + j * 16 + ccol;
    const float bv = bias[col];
#pragma unroll
    for (int i = 0; i < 4; ++i) {
      const size_t rb = (size_t)(mBase + wm + i * 16 + crow) * OUT_F + col;
#pragma unroll
      for (int t = 0; t < 4; ++t)
        C[rb + (size_t)t * OUT_F] = acc[i][j][t] + bv;
    }
  }
}

extern "C" void kernel_launch(void* const* d_in, const int* in_sizes, int n_in,
                              void* d_out, int out_size, void* d_ws, size_t ws_size,
                              hipStream_t stream) {
  const float* x  = (const float*)d_in[0];
  const int*   wp = (const int*)d_in[1];
  const float* sc = (const float*)d_in[2];
  const float* bi = (const float*)d_in[3];
  float* out = (float*)d_out;

  const size_t bBytes = (size_t)OUT_F * IN_F * 2;   // 33.5 MB bf16 W
  const size_t aBytes = (size_t)M_TOT * IN_F * 2;   // 67 MB bf16 x

  if (ws_size >= aBytes + bBytes) {
    u16* B = (u16*)d_ws;
    u16* A = (u16*)((char*)d_ws + bBytes);
    k_prep<<<4608, 256, 0, stream>>>(x, A, wp, sc, B);
    k_gemm256<<<(M_TOT / BM2) * (OUT_F / BN2), 512, 0, stream>>>(A, B, bi, out);
  } else {
    dim3 grid(OUT_F / BN, M_TOT / BM);
    k_gemm_fused<<<grid, 256, 0, stream>>>(x, wp, sc, bi, out);
  }
}